// Round 7
// baseline (206.044 us; speedup 1.0000x reference)
//
#include <hip/hip_runtime.h>
#include <math.h>

#define BDIM 64
#define HDIM 512
#define WDIM 512
#define KW   31
#define PAD  15
#define INV_KK (1.0f / 961.0f)
#define TH   32                       // output rows per block (grid 64x16 = 1024 blocks)
#define NBLK (BDIM * (HDIM / TH))     // 1024
#define NPIX ((size_t)BDIM * HDIM * WDIM)

// acc[0]: bce sum; acc[1..64]: inter[b]; acc[65..128]: union[b]; acc[129]: done-counter
#define NACC 130

// ---- DPP helpers: VALU cross-lane (no LDS pipe) -------------------------
template<int CTRL, int RMASK>
__device__ __forceinline__ float dpp_add(float p) {
    int t = __builtin_amdgcn_update_dpp(0, __builtin_bit_cast(int, p),
                                        CTRL, RMASK, 0xf, true);
    return p + __builtin_bit_cast(float, t);
}

// inclusive prefix sum over 64 lanes
__device__ __forceinline__ float wave_iscan(float p) {
    p = dpp_add<0x111, 0xf>(p);   // row_shr:1
    p = dpp_add<0x112, 0xf>(p);   // row_shr:2
    p = dpp_add<0x114, 0xf>(p);   // row_shr:4
    p = dpp_add<0x118, 0xf>(p);   // row_shr:8
    p = dpp_add<0x142, 0xa>(p);   // row_bcast:15 -> rows 1,3
    p = dpp_add<0x143, 0xc>(p);   // row_bcast:31 -> rows 2,3
    return p;
}

// inclusive prefix valid through lane 31 (we only use lanes 0..29)
__device__ __forceinline__ float wave_iscan30(float p) {
    p = dpp_add<0x111, 0xf>(p);
    p = dpp_add<0x112, 0xf>(p);
    p = dpp_add<0x114, 0xf>(p);
    p = dpp_add<0x118, 0xf>(p);
    p = dpp_add<0x142, 0xa>(p);
    return p;
}

// lane i <- lane i-1 (lane 0 -> 0): inclusive->exclusive shift
__device__ __forceinline__ float wave_shr1(float p) {
    int t = __builtin_amdgcn_update_dpp(0, __builtin_bit_cast(int, p),
                                        0x138 /*WAVE_SHR1*/, 0xf, 0xf, true);
    return __builtin_bit_cast(float, t);
}

__device__ __forceinline__ float bperm(int idx, float v) {
    return __builtin_bit_cast(float,
        __builtin_amdgcn_ds_bpermute(idx, __builtin_bit_cast(int, v)));
}

__device__ __forceinline__ float readlane63(float v) {
    return __builtin_bit_cast(float,
        __builtin_amdgcn_readlane(__builtin_bit_cast(int, v), 63));
}

// Vertical-first separable box filter, ring-free. EXACT R6 fused body (the
// ~70us champion: rolled loops, guarded loads, 1-deep rotate pipeline,
// single-bpermute merge, prologue loads hoisted above warmup). New in R7:
// single-dispatch structure — workspace zeroed by hipMemsetAsync, finalize
// folded in via a last-block-done tail (device-scope atomics + threadfence;
// coherent re-reads via atomicAdd(p, 0.0)). Finalize math is bit-identical
// to the old finalize_kernel.
__global__ __launch_bounds__(512, 8)
void fused_kernel(const float* __restrict__ pred,
                  const float* __restrict__ mask,
                  double* __restrict__ acc,
                  float* __restrict__ out) {
    __shared__ float red[3][8];
    __shared__ int is_last;

    const int b    = blockIdx.x;
    const int y0   = blockIdx.y * TH;
    const int x    = threadIdx.x;     // output column
    const int lane = x & 63;
    const int wv   = x >> 6;
    const int s    = wv * 64;         // strip start column

    const float* mbase = mask + (size_t)b * HDIM * WDIM;
    const float* pbase = pred + (size_t)b * HDIM * WDIM;

    const int acol = s - 15 + lane;             // halo column, pos 0..63
    const int bcol = s + 49 + lane;             // halo column, pos 64..93
    const bool a_ok = (acol >= 0) && (acol < WDIM);
    const bool b_ok = (lane < 30) && (bcol < WDIM);

    const int  i30  = ((lane + 30) & 63) << 2;  // hoisted bpermute byte index
    const bool lo30 = (lane <= 29);             // z-merge select
    const bool lo34 = (lane <= 33);             // Phi select

    const int tstart = y0 - PAD;                // first row entering the vsum
    const int tend   = y0 + TH - 1 + PAD;       // last input row (62 total)
    const int smax   = (tstart > 0) ? tstart : 0;  // earliest valid subtracted row

    float vsA = 0.f, vsB = 0.f;                 // vertical 31-row column sums
    float bce_acc = 0.f, inter_acc = 0.f, uni_acc = 0.f;

    auto ld_halo = [&](int row, float& A, float& B) {
        A = 0.f; B = 0.f;
        if (row >= 0 && row < HDIM) {           // wave-uniform branch
            const float* rp = mbase + (size_t)row * WDIM;
            if (a_ok) A = rp[acol];             // exec-masked
            if (b_ok) B = rp[bcol];
        }
    };
    auto ld_sub = [&](int row, float& S, float& T) {
        S = 0.f; T = 0.f;
        if (row >= smax) {                      // wave-uniform branch
            const float* rp = mbase + (size_t)row * WDIM;
            if (a_ok) S = rp[acol];
            if (b_ok) T = rp[bcol];
        }
    };
    auto ld_emit = [&](int row, float& M, float& P) {
        M = 0.f; P = 0.f;
        if (row <= tend) {                      // prefetch-past-end guard
            const size_t off = (size_t)(row - PAD) * WDIM + x;
            M = mbase[off];
            P = pbase[off];
        }
    };

    auto process = [&](float A, float B, float S, float T, float M, float P) {
        vsA += A - S;                       // slide vertical window
        vsB += B - T;
        float pa = wave_iscan(vsA);         // prefix over positions 0..63
        float pb = wave_iscan30(vsB);       // prefix over positions 64..93
        const float atot = readlane63(pa);
        const float z   = lo30 ? pb : pa;   // disjoint source ranges -> merge
        const float bp  = bperm(i30, z);    // lane<=33: pa[l+30]; else pb[l-34]
        const float Phi = lo34 ? bp : (atot + bp);
        const float Plo = wave_shr1(pa);
        const float hs  = Phi - Plo;        // full 31x31 box sum

        const float box  = hs * INV_KK;
        const float weit = 1.f + 5.f * fabsf(box - M);
        const float e1   = __expf(-fabsf(P));
        const float bce  = fmaxf(P, 0.f) - P * M + __logf(1.f + e1);
        const float rr   = __builtin_amdgcn_rcpf(1.f + e1);
        const float sp   = (P >= 0.f) ? rr : e1 * rr;    // sigmoid from e1
        bce_acc   += bce;
        inter_acc += sp * M * weit;
        uni_acc   += (sp + M) * weit;
    };

    const int t0 = y0 + PAD;                 // first emit-phase input row

    // ---- prologue: warmup stages + emit-phase prologue loads (early) ----
    float cA[2], cB[2], xA[2], xB[2];
    ld_halo(tstart,     cA[0], cB[0]);
    ld_halo(tstart + 1, cA[1], cB[1]);
    ld_halo(tstart + 2, xA[0], xB[0]);
    ld_halo(tstart + 3, xA[1], xB[1]);

    float cS[2], cT[2], cM[2], cP[2];        // emit rows t0, t0+1
    float nS[2], nT[2], nM[2], nQ[2];        // emit rows t0+2, t0+3
    ld_sub (t0 - 31, cS[0], cT[0]);          // masked to 0 unless y0>0
    ld_sub (t0 - 30, cS[1], cT[1]);
    ld_sub (t0 - 29, nS[0], nT[0]);
    ld_sub (t0 - 28, nS[1], nT[1]);
    ld_emit(t0,      cM[0], cP[0]);
    ld_emit(t0 + 1,  cM[1], cP[1]);
    ld_emit(t0 + 2,  nM[0], nQ[0]);
    ld_emit(t0 + 3,  nM[1], nQ[1]);

    // ---- warmup: rows tstart .. y0+14 (30 rows, 15 iters), adds only ----
    for (int t = tstart; t < t0; t += 2) {
        float nA[2], nB[2];
        ld_halo(t + 4, nA[0], nB[0]);
        ld_halo(t + 5, nA[1], nB[1]);
        vsA += cA[0] + cA[1];
        vsB += cB[0] + cB[1];
        cA[0] = xA[0]; cA[1] = xA[1]; cB[0] = xB[0]; cB[1] = xB[1];
        xA[0] = nA[0]; xA[1] = nA[1]; xB[0] = nB[0]; xB[1] = nB[1];
    }
    // cA/cB = rows t0, t0+1 ; xA/xB = rows t0+2, t0+3 (already loaded)

    // ---- emit: rows t0 .. t0+31 -> outputs y0 .. y0+31 ----
    for (int t = t0; t <= tend; t += 2) {
        float nA[2], nB[2], mS[2], mT[2], mM[2], mQ[2];
        ld_halo(t + 4, nA[0], nB[0]);
        ld_halo(t + 5, nA[1], nB[1]);
        ld_sub (t - 27, mS[0], mT[0]);       // (t+4)-31
        ld_sub (t - 26, mS[1], mT[1]);       // (t+5)-31
        ld_emit(t + 4, mM[0], mQ[0]);
        ld_emit(t + 5, mM[1], mQ[1]);

        process(cA[0], cB[0], cS[0], cT[0], cM[0], cP[0]);
        process(cA[1], cB[1], cS[1], cT[1], cM[1], cP[1]);

        cA[0] = xA[0]; cA[1] = xA[1]; cB[0] = xB[0]; cB[1] = xB[1];
        cS[0] = nS[0]; cS[1] = nS[1]; cT[0] = nT[0]; cT[1] = nT[1];
        cM[0] = nM[0]; cM[1] = nM[1]; cP[0] = nQ[0]; cP[1] = nQ[1];
        xA[0] = nA[0]; xA[1] = nA[1]; xB[0] = nB[0]; xB[1] = nB[1];
        nS[0] = mS[0]; nS[1] = mS[1]; nT[0] = mT[0]; nT[1] = mT[1];
        nM[0] = mM[0]; nM[1] = mM[1]; nQ[0] = mQ[0]; nQ[1] = mQ[1];
    }

    // ---- block reduction (8 waves) ----
#pragma unroll
    for (int off = 32; off > 0; off >>= 1) {
        bce_acc   += __shfl_down(bce_acc, off);
        inter_acc += __shfl_down(inter_acc, off);
        uni_acc   += __shfl_down(uni_acc, off);
    }
    if (lane == 0) {
        red[0][wv] = bce_acc;
        red[1][wv] = inter_acc;
        red[2][wv] = uni_acc;
    }
    __syncthreads();
    if (threadIdx.x == 0) {
        float bs = 0.f, is = 0.f, us = 0.f;
#pragma unroll
        for (int w = 0; w < 8; ++w) { bs += red[0][w]; is += red[1][w]; us += red[2][w]; }
        atomicAdd(&acc[0],      (double)bs);
        atomicAdd(&acc[1 + b],  (double)is);
        atomicAdd(&acc[65 + b], (double)us);
        // publish this block's contributions, then bump the done-counter
        __threadfence();
        unsigned prev = atomicAdd(reinterpret_cast<unsigned*>(acc + 129), 1u);
        is_last = (prev == NBLK - 1) ? 1 : 0;
    }
    __syncthreads();

    // ---- last block performs finalize (identical math to old finalize_kernel)
    if (is_last && wv == 0) {
        // coherent cross-XCD reads: atomic RMW with 0.0 returns current value
        double inter = atomicAdd(&acc[1 + lane],  0.0);
        double uni   = atomicAdd(&acc[65 + lane], 0.0);
        double wiou  = 1.0 - (inter + 1.0) / (uni - inter + 1.0);
#pragma unroll
        for (int off = 32; off > 0; off >>= 1) wiou += __shfl_down(wiou, off);
        if (lane == 0) {
            double wbce = atomicAdd(&acc[0], 0.0) / (double)NPIX;
            out[0] = (float)(wbce + wiou / (double)BDIM);
        }
    }
}

extern "C" void kernel_launch(void* const* d_in, const int* in_sizes, int n_in,
                              void* d_out, int out_size, void* d_ws, size_t ws_size,
                              hipStream_t stream) {
    const float* pred = (const float*)d_in[0];
    const float* mask = (const float*)d_in[1];
    float* out = (float*)d_out;
    double* acc = (double*)d_ws;

    // zero acc[0..128] + done-counter (acc[129]) in one graph-capturable node
    hipMemsetAsync(d_ws, 0, NACC * sizeof(double), stream);

    dim3 grid(BDIM, HDIM / TH);
    fused_kernel<<<grid, WDIM, 0, stream>>>(pred, mask, acc, out);
}

// Round 8
// 168.052 us; speedup vs baseline: 1.2261x; 1.2261x over previous
//
#include <hip/hip_runtime.h>
#include <math.h>

#define BDIM 64
#define HDIM 512
#define WDIM 512
#define KW   31
#define PAD  15
#define INV_KK (1.0f / 961.0f)
#define TH   32                       // output rows per block (grid 64x16 = 1024 blocks)
#define NPIX ((size_t)BDIM * HDIM * WDIM)

// acc[0]: bce sum; acc[1..64]: inter[b]; acc[65..128]: union[b]
#define NACC 129

__global__ void zero_acc_kernel(double* acc) {
    int i = threadIdx.x;
    if (i < NACC) acc[i] = 0.0;
}

// ---- DPP helpers: VALU cross-lane (no LDS pipe) -------------------------
template<int CTRL, int RMASK>
__device__ __forceinline__ float dpp_add(float p) {
    int t = __builtin_amdgcn_update_dpp(0, __builtin_bit_cast(int, p),
                                        CTRL, RMASK, 0xf, true);
    return p + __builtin_bit_cast(float, t);
}

// inclusive prefix sum over 64 lanes
__device__ __forceinline__ float wave_iscan(float p) {
    p = dpp_add<0x111, 0xf>(p);   // row_shr:1
    p = dpp_add<0x112, 0xf>(p);   // row_shr:2
    p = dpp_add<0x114, 0xf>(p);   // row_shr:4
    p = dpp_add<0x118, 0xf>(p);   // row_shr:8
    p = dpp_add<0x142, 0xa>(p);   // row_bcast:15 -> rows 1,3
    p = dpp_add<0x143, 0xc>(p);   // row_bcast:31 -> rows 2,3
    return p;
}

// inclusive prefix valid through lane 31 (we only use lanes 0..29)
__device__ __forceinline__ float wave_iscan30(float p) {
    p = dpp_add<0x111, 0xf>(p);
    p = dpp_add<0x112, 0xf>(p);
    p = dpp_add<0x114, 0xf>(p);
    p = dpp_add<0x118, 0xf>(p);
    p = dpp_add<0x142, 0xa>(p);
    return p;
}

// lane i <- lane i-1 (lane 0 -> 0): inclusive->exclusive shift
__device__ __forceinline__ float wave_shr1(float p) {
    int t = __builtin_amdgcn_update_dpp(0, __builtin_bit_cast(int, p),
                                        0x138 /*WAVE_SHR1*/, 0xf, 0xf, true);
    return __builtin_bit_cast(float, t);
}

__device__ __forceinline__ float bperm(int idx, float v) {
    return __builtin_bit_cast(float,
        __builtin_amdgcn_ds_bpermute(idx, __builtin_bit_cast(int, v)));
}

__device__ __forceinline__ float readlane63(float v) {
    return __builtin_bit_cast(float,
        __builtin_amdgcn_readlane(__builtin_bit_cast(int, v), 63));
}

// Vertical-first separable box filter, ring-free. EXACT R6 structure (the
// ~70us champion: rolled loops, guarded loads, 1-deep rotate pipeline,
// single-bpermute merge, prologue loads hoisted above warmup, three-kernel
// launch — R7's single-dispatch fold REGRESSED the body 70->106us and is
// fully reverted). New in R8: s_setprio(1) around each process pair.
// Mechanism (T5): no barriers in the main loop -> the 8 waves drift into
// different phases (load-issuing vs compute-chain); raising priority during
// the serial scan->bperm->exp chain wins issue arbitration, shortening the
// critical chain (attn-like regime where setprio measured +4-7%).
__global__ __launch_bounds__(512, 8)
void fused_kernel(const float* __restrict__ pred,
                  const float* __restrict__ mask,
                  double* __restrict__ acc) {
    __shared__ float red[3][8];

    const int b    = blockIdx.x;
    const int y0   = blockIdx.y * TH;
    const int x    = threadIdx.x;     // output column
    const int lane = x & 63;
    const int wv   = x >> 6;
    const int s    = wv * 64;         // strip start column

    const float* mbase = mask + (size_t)b * HDIM * WDIM;
    const float* pbase = pred + (size_t)b * HDIM * WDIM;

    const int acol = s - 15 + lane;             // halo column, pos 0..63
    const int bcol = s + 49 + lane;             // halo column, pos 64..93
    const bool a_ok = (acol >= 0) && (acol < WDIM);
    const bool b_ok = (lane < 30) && (bcol < WDIM);

    const int  i30  = ((lane + 30) & 63) << 2;  // hoisted bpermute byte index
    const bool lo30 = (lane <= 29);             // z-merge select
    const bool lo34 = (lane <= 33);             // Phi select

    const int tstart = y0 - PAD;                // first row entering the vsum
    const int tend   = y0 + TH - 1 + PAD;       // last input row (62 total)
    const int smax   = (tstart > 0) ? tstart : 0;  // earliest valid subtracted row

    float vsA = 0.f, vsB = 0.f;                 // vertical 31-row column sums
    float bce_acc = 0.f, inter_acc = 0.f, uni_acc = 0.f;

    auto ld_halo = [&](int row, float& A, float& B) {
        A = 0.f; B = 0.f;
        if (row >= 0 && row < HDIM) {           // wave-uniform branch
            const float* rp = mbase + (size_t)row * WDIM;
            if (a_ok) A = rp[acol];             // exec-masked
            if (b_ok) B = rp[bcol];
        }
    };
    auto ld_sub = [&](int row, float& S, float& T) {
        S = 0.f; T = 0.f;
        if (row >= smax) {                      // wave-uniform branch
            const float* rp = mbase + (size_t)row * WDIM;
            if (a_ok) S = rp[acol];
            if (b_ok) T = rp[bcol];
        }
    };
    auto ld_emit = [&](int row, float& M, float& P) {
        M = 0.f; P = 0.f;
        if (row <= tend) {                      // prefetch-past-end guard
            const size_t off = (size_t)(row - PAD) * WDIM + x;
            M = mbase[off];
            P = pbase[off];
        }
    };

    auto process = [&](float A, float B, float S, float T, float M, float P) {
        vsA += A - S;                       // slide vertical window
        vsB += B - T;
        float pa = wave_iscan(vsA);         // prefix over positions 0..63
        float pb = wave_iscan30(vsB);       // prefix over positions 64..93
        const float atot = readlane63(pa);
        const float z   = lo30 ? pb : pa;   // disjoint source ranges -> merge
        const float bp  = bperm(i30, z);    // lane<=33: pa[l+30]; else pb[l-34]
        const float Phi = lo34 ? bp : (atot + bp);
        const float Plo = wave_shr1(pa);
        const float hs  = Phi - Plo;        // full 31x31 box sum

        const float box  = hs * INV_KK;
        const float weit = 1.f + 5.f * fabsf(box - M);
        const float e1   = __expf(-fabsf(P));
        const float bce  = fmaxf(P, 0.f) - P * M + __logf(1.f + e1);
        const float rr   = __builtin_amdgcn_rcpf(1.f + e1);
        const float sp   = (P >= 0.f) ? rr : e1 * rr;    // sigmoid from e1
        bce_acc   += bce;
        inter_acc += sp * M * weit;
        uni_acc   += (sp + M) * weit;
    };

    const int t0 = y0 + PAD;                 // first emit-phase input row

    // ---- prologue: warmup stages + emit-phase prologue loads (early) ----
    float cA[2], cB[2], xA[2], xB[2];
    ld_halo(tstart,     cA[0], cB[0]);
    ld_halo(tstart + 1, cA[1], cB[1]);
    ld_halo(tstart + 2, xA[0], xB[0]);
    ld_halo(tstart + 3, xA[1], xB[1]);

    float cS[2], cT[2], cM[2], cP[2];        // emit rows t0, t0+1
    float nS[2], nT[2], nM[2], nQ[2];        // emit rows t0+2, t0+3
    ld_sub (t0 - 31, cS[0], cT[0]);          // masked to 0 unless y0>0
    ld_sub (t0 - 30, cS[1], cT[1]);
    ld_sub (t0 - 29, nS[0], nT[0]);
    ld_sub (t0 - 28, nS[1], nT[1]);
    ld_emit(t0,      cM[0], cP[0]);
    ld_emit(t0 + 1,  cM[1], cP[1]);
    ld_emit(t0 + 2,  nM[0], nQ[0]);
    ld_emit(t0 + 3,  nM[1], nQ[1]);

    // ---- warmup: rows tstart .. y0+14 (30 rows, 15 iters), adds only ----
    for (int t = tstart; t < t0; t += 2) {
        float nA[2], nB[2];
        ld_halo(t + 4, nA[0], nB[0]);
        ld_halo(t + 5, nA[1], nB[1]);
        vsA += cA[0] + cA[1];
        vsB += cB[0] + cB[1];
        cA[0] = xA[0]; cA[1] = xA[1]; cB[0] = xB[0]; cB[1] = xB[1];
        xA[0] = nA[0]; xA[1] = nA[1]; xB[0] = nB[0]; xB[1] = nB[1];
    }
    // cA/cB = rows t0, t0+1 ; xA/xB = rows t0+2, t0+3 (already loaded)

    // ---- emit: rows t0 .. t0+31 -> outputs y0 .. y0+31 ----
    for (int t = t0; t <= tend; t += 2) {
        float nA[2], nB[2], mS[2], mT[2], mM[2], mQ[2];
        ld_halo(t + 4, nA[0], nB[0]);
        ld_halo(t + 5, nA[1], nB[1]);
        ld_sub (t - 27, mS[0], mT[0]);       // (t+4)-31
        ld_sub (t - 26, mS[1], mT[1]);       // (t+5)-31
        ld_emit(t + 4, mM[0], mQ[0]);
        ld_emit(t + 5, mM[1], mQ[1]);

        __builtin_amdgcn_s_setprio(1);       // favor the serial compute chain
        process(cA[0], cB[0], cS[0], cT[0], cM[0], cP[0]);
        process(cA[1], cB[1], cS[1], cT[1], cM[1], cP[1]);
        __builtin_amdgcn_s_setprio(0);

        cA[0] = xA[0]; cA[1] = xA[1]; cB[0] = xB[0]; cB[1] = xB[1];
        cS[0] = nS[0]; cS[1] = nS[1]; cT[0] = nT[0]; cT[1] = nT[1];
        cM[0] = nM[0]; cM[1] = nM[1]; cP[0] = nQ[0]; cP[1] = nQ[1];
        xA[0] = nA[0]; xA[1] = nA[1]; xB[0] = nB[0]; xB[1] = nB[1];
        nS[0] = mS[0]; nS[1] = mS[1]; nT[0] = mT[0]; nT[1] = mT[1];
        nM[0] = mM[0]; nM[1] = mM[1]; nQ[0] = mQ[0]; nQ[1] = mQ[1];
    }

    // ---- block reduction (8 waves) ----
#pragma unroll
    for (int off = 32; off > 0; off >>= 1) {
        bce_acc   += __shfl_down(bce_acc, off);
        inter_acc += __shfl_down(inter_acc, off);
        uni_acc   += __shfl_down(uni_acc, off);
    }
    if (lane == 0) {
        red[0][wv] = bce_acc;
        red[1][wv] = inter_acc;
        red[2][wv] = uni_acc;
    }
    __syncthreads();
    if (threadIdx.x == 0) {
        float bs = 0.f, is = 0.f, us = 0.f;
#pragma unroll
        for (int w = 0; w < 8; ++w) { bs += red[0][w]; is += red[1][w]; us += red[2][w]; }
        atomicAdd(&acc[0],      (double)bs);
        atomicAdd(&acc[1 + b],  (double)is);
        atomicAdd(&acc[65 + b], (double)us);
    }
}

__global__ void finalize_kernel(const double* __restrict__ acc, float* __restrict__ out) {
    const int b = threadIdx.x;   // one wave
    double inter = acc[1 + b];
    double uni   = acc[65 + b];
    double wiou  = 1.0 - (inter + 1.0) / (uni - inter + 1.0);
#pragma unroll
    for (int off = 32; off > 0; off >>= 1) wiou += __shfl_down(wiou, off);
    if (b == 0) {
        double wbce = acc[0] / (double)NPIX;
        out[0] = (float)(wbce + wiou / (double)BDIM);
    }
}

extern "C" void kernel_launch(void* const* d_in, const int* in_sizes, int n_in,
                              void* d_out, int out_size, void* d_ws, size_t ws_size,
                              hipStream_t stream) {
    const float* pred = (const float*)d_in[0];
    const float* mask = (const float*)d_in[1];
    float* out = (float*)d_out;
    double* acc = (double*)d_ws;

    zero_acc_kernel<<<1, 256, 0, stream>>>(acc);

    dim3 grid(BDIM, HDIM / TH);
    fused_kernel<<<grid, WDIM, 0, stream>>>(pred, mask, acc);

    finalize_kernel<<<1, 64, 0, stream>>>(acc, out);
}

// Round 9
// 161.773 us; speedup vs baseline: 1.2737x; 1.0388x over previous
//
#include <hip/hip_runtime.h>
#include <math.h>

#define BDIM 64
#define HDIM 512
#define WDIM 512
#define KW   31
#define PAD  15
#define INV_KK (1.0f / 961.0f)
#define TH   64                       // output rows per block (grid 64x8 = 512 blocks)
#define NPIX ((size_t)BDIM * HDIM * WDIM)

// acc[0]: bce sum; acc[1..64]: inter[b]; acc[65..128]: union[b]
#define NACC 129

__global__ void zero_acc_kernel(double* acc) {
    int i = threadIdx.x;
    if (i < NACC) acc[i] = 0.0;
}

// ---- DPP helpers: VALU cross-lane (no LDS pipe) -------------------------
template<int CTRL, int RMASK>
__device__ __forceinline__ float dpp_add(float p) {
    int t = __builtin_amdgcn_update_dpp(0, __builtin_bit_cast(int, p),
                                        CTRL, RMASK, 0xf, true);
    return p + __builtin_bit_cast(float, t);
}

// inclusive prefix sum over 64 lanes
__device__ __forceinline__ float wave_iscan(float p) {
    p = dpp_add<0x111, 0xf>(p);   // row_shr:1
    p = dpp_add<0x112, 0xf>(p);   // row_shr:2
    p = dpp_add<0x114, 0xf>(p);   // row_shr:4
    p = dpp_add<0x118, 0xf>(p);   // row_shr:8
    p = dpp_add<0x142, 0xa>(p);   // row_bcast:15 -> rows 1,3
    p = dpp_add<0x143, 0xc>(p);   // row_bcast:31 -> rows 2,3
    return p;
}

// inclusive prefix valid through lane 31 (we only use lanes 0..29)
__device__ __forceinline__ float wave_iscan30(float p) {
    p = dpp_add<0x111, 0xf>(p);
    p = dpp_add<0x112, 0xf>(p);
    p = dpp_add<0x114, 0xf>(p);
    p = dpp_add<0x118, 0xf>(p);
    p = dpp_add<0x142, 0xa>(p);
    return p;
}

// lane i <- lane i-1 (lane 0 -> 0): inclusive->exclusive shift
__device__ __forceinline__ float wave_shr1(float p) {
    int t = __builtin_amdgcn_update_dpp(0, __builtin_bit_cast(int, p),
                                        0x138 /*WAVE_SHR1*/, 0xf, 0xf, true);
    return __builtin_bit_cast(float, t);
}

__device__ __forceinline__ float bperm(int idx, float v) {
    return __builtin_bit_cast(float,
        __builtin_amdgcn_ds_bpermute(idx, __builtin_bit_cast(int, v)));
}

__device__ __forceinline__ float readlane63(float v) {
    return __builtin_bit_cast(float,
        __builtin_amdgcn_readlane(__builtin_bit_cast(int, v), 63));
}

// Vertical-first separable box filter, ring-free. EXACT R8 body (the 66us
// champion: rolled loops, guarded loads, 1-deep rotate pipeline, single-
// bpermute merge, prologue loads hoisted above warmup, setprio around the
// compute cluster, three-kernel launch). New in R9: TH 32 -> 64.
// Warmup amortization: 30 warmup rows now serve 64 emit rows (read/scan
// amplification 1.94 -> 1.47), cutting per-CU issue work ~14% and mask
// FETCH ~10%. Cost: 2 blocks/CU (16 waves) instead of 4 (32) — R0 vs R1
// bounded the TLP sensitivity of this body at ~6%.
__global__ __launch_bounds__(512, 8)
void fused_kernel(const float* __restrict__ pred,
                  const float* __restrict__ mask,
                  double* __restrict__ acc) {
    __shared__ float red[3][8];

    const int b    = blockIdx.x;
    const int y0   = blockIdx.y * TH;
    const int x    = threadIdx.x;     // output column
    const int lane = x & 63;
    const int wv   = x >> 6;
    const int s    = wv * 64;         // strip start column

    const float* mbase = mask + (size_t)b * HDIM * WDIM;
    const float* pbase = pred + (size_t)b * HDIM * WDIM;

    const int acol = s - 15 + lane;             // halo column, pos 0..63
    const int bcol = s + 49 + lane;             // halo column, pos 64..93
    const bool a_ok = (acol >= 0) && (acol < WDIM);
    const bool b_ok = (lane < 30) && (bcol < WDIM);

    const int  i30  = ((lane + 30) & 63) << 2;  // hoisted bpermute byte index
    const bool lo30 = (lane <= 29);             // z-merge select
    const bool lo34 = (lane <= 33);             // Phi select

    const int tstart = y0 - PAD;                // first row entering the vsum
    const int tend   = y0 + TH - 1 + PAD;       // last input row
    const int smax   = (tstart > 0) ? tstart : 0;  // earliest valid subtracted row

    float vsA = 0.f, vsB = 0.f;                 // vertical 31-row column sums
    float bce_acc = 0.f, inter_acc = 0.f, uni_acc = 0.f;

    auto ld_halo = [&](int row, float& A, float& B) {
        A = 0.f; B = 0.f;
        if (row >= 0 && row < HDIM) {           // wave-uniform branch
            const float* rp = mbase + (size_t)row * WDIM;
            if (a_ok) A = rp[acol];             // exec-masked
            if (b_ok) B = rp[bcol];
        }
    };
    auto ld_sub = [&](int row, float& S, float& T) {
        S = 0.f; T = 0.f;
        if (row >= smax) {                      // wave-uniform branch
            const float* rp = mbase + (size_t)row * WDIM;
            if (a_ok) S = rp[acol];
            if (b_ok) T = rp[bcol];
        }
    };
    auto ld_emit = [&](int row, float& M, float& P) {
        M = 0.f; P = 0.f;
        if (row <= tend) {                      // prefetch-past-end guard
            const size_t off = (size_t)(row - PAD) * WDIM + x;
            M = mbase[off];
            P = pbase[off];
        }
    };

    auto process = [&](float A, float B, float S, float T, float M, float P) {
        vsA += A - S;                       // slide vertical window
        vsB += B - T;
        float pa = wave_iscan(vsA);         // prefix over positions 0..63
        float pb = wave_iscan30(vsB);       // prefix over positions 64..93
        const float atot = readlane63(pa);
        const float z   = lo30 ? pb : pa;   // disjoint source ranges -> merge
        const float bp  = bperm(i30, z);    // lane<=33: pa[l+30]; else pb[l-34]
        const float Phi = lo34 ? bp : (atot + bp);
        const float Plo = wave_shr1(pa);
        const float hs  = Phi - Plo;        // full 31x31 box sum

        const float box  = hs * INV_KK;
        const float weit = 1.f + 5.f * fabsf(box - M);
        const float e1   = __expf(-fabsf(P));
        const float bce  = fmaxf(P, 0.f) - P * M + __logf(1.f + e1);
        const float rr   = __builtin_amdgcn_rcpf(1.f + e1);
        const float sp   = (P >= 0.f) ? rr : e1 * rr;    // sigmoid from e1
        bce_acc   += bce;
        inter_acc += sp * M * weit;
        uni_acc   += (sp + M) * weit;
    };

    const int t0 = y0 + PAD;                 // first emit-phase input row

    // ---- prologue: warmup stages + emit-phase prologue loads (early) ----
    float cA[2], cB[2], xA[2], xB[2];
    ld_halo(tstart,     cA[0], cB[0]);
    ld_halo(tstart + 1, cA[1], cB[1]);
    ld_halo(tstart + 2, xA[0], xB[0]);
    ld_halo(tstart + 3, xA[1], xB[1]);

    float cS[2], cT[2], cM[2], cP[2];        // emit rows t0, t0+1
    float nS[2], nT[2], nM[2], nQ[2];        // emit rows t0+2, t0+3
    ld_sub (t0 - 31, cS[0], cT[0]);          // masked to 0 unless y0>0
    ld_sub (t0 - 30, cS[1], cT[1]);
    ld_sub (t0 - 29, nS[0], nT[0]);
    ld_sub (t0 - 28, nS[1], nT[1]);
    ld_emit(t0,      cM[0], cP[0]);
    ld_emit(t0 + 1,  cM[1], cP[1]);
    ld_emit(t0 + 2,  nM[0], nQ[0]);
    ld_emit(t0 + 3,  nM[1], nQ[1]);

    // ---- warmup: rows tstart .. y0+14 (30 rows, 15 iters), adds only ----
    for (int t = tstart; t < t0; t += 2) {
        float nA[2], nB[2];
        ld_halo(t + 4, nA[0], nB[0]);
        ld_halo(t + 5, nA[1], nB[1]);
        vsA += cA[0] + cA[1];
        vsB += cB[0] + cB[1];
        cA[0] = xA[0]; cA[1] = xA[1]; cB[0] = xB[0]; cB[1] = xB[1];
        xA[0] = nA[0]; xA[1] = nA[1]; xB[0] = nB[0]; xB[1] = nB[1];
    }
    // cA/cB = rows t0, t0+1 ; xA/xB = rows t0+2, t0+3 (already loaded)

    // ---- emit: rows t0 .. t0+TH-1 -> outputs y0 .. y0+TH-1 ----
    for (int t = t0; t <= tend; t += 2) {
        float nA[2], nB[2], mS[2], mT[2], mM[2], mQ[2];
        ld_halo(t + 4, nA[0], nB[0]);
        ld_halo(t + 5, nA[1], nB[1]);
        ld_sub (t - 27, mS[0], mT[0]);       // (t+4)-31
        ld_sub (t - 26, mS[1], mT[1]);       // (t+5)-31
        ld_emit(t + 4, mM[0], mQ[0]);
        ld_emit(t + 5, mM[1], mQ[1]);

        __builtin_amdgcn_s_setprio(1);       // favor the serial compute chain
        process(cA[0], cB[0], cS[0], cT[0], cM[0], cP[0]);
        process(cA[1], cB[1], cS[1], cT[1], cM[1], cP[1]);
        __builtin_amdgcn_s_setprio(0);

        cA[0] = xA[0]; cA[1] = xA[1]; cB[0] = xB[0]; cB[1] = xB[1];
        cS[0] = nS[0]; cS[1] = nS[1]; cT[0] = nT[0]; cT[1] = nT[1];
        cM[0] = nM[0]; cM[1] = nM[1]; cP[0] = nQ[0]; cP[1] = nQ[1];
        xA[0] = nA[0]; xA[1] = nA[1]; xB[0] = nB[0]; xB[1] = nB[1];
        nS[0] = mS[0]; nS[1] = mS[1]; nT[0] = mT[0]; nT[1] = mT[1];
        nM[0] = mM[0]; nM[1] = mM[1]; nQ[0] = mQ[0]; nQ[1] = mQ[1];
    }

    // ---- block reduction (8 waves) ----
#pragma unroll
    for (int off = 32; off > 0; off >>= 1) {
        bce_acc   += __shfl_down(bce_acc, off);
        inter_acc += __shfl_down(inter_acc, off);
        uni_acc   += __shfl_down(uni_acc, off);
    }
    if (lane == 0) {
        red[0][wv] = bce_acc;
        red[1][wv] = inter_acc;
        red[2][wv] = uni_acc;
    }
    __syncthreads();
    if (threadIdx.x == 0) {
        float bs = 0.f, is = 0.f, us = 0.f;
#pragma unroll
        for (int w = 0; w < 8; ++w) { bs += red[0][w]; is += red[1][w]; us += red[2][w]; }
        atomicAdd(&acc[0],      (double)bs);
        atomicAdd(&acc[1 + b],  (double)is);
        atomicAdd(&acc[65 + b], (double)us);
    }
}

__global__ void finalize_kernel(const double* __restrict__ acc, float* __restrict__ out) {
    const int b = threadIdx.x;   // one wave
    double inter = acc[1 + b];
    double uni   = acc[65 + b];
    double wiou  = 1.0 - (inter + 1.0) / (uni - inter + 1.0);
#pragma unroll
    for (int off = 32; off > 0; off >>= 1) wiou += __shfl_down(wiou, off);
    if (b == 0) {
        double wbce = acc[0] / (double)NPIX;
        out[0] = (float)(wbce + wiou / (double)BDIM);
    }
}

extern "C" void kernel_launch(void* const* d_in, const int* in_sizes, int n_in,
                              void* d_out, int out_size, void* d_ws, size_t ws_size,
                              hipStream_t stream) {
    const float* pred = (const float*)d_in[0];
    const float* mask = (const float*)d_in[1];
    float* out = (float*)d_out;
    double* acc = (double*)d_ws;

    zero_acc_kernel<<<1, 256, 0, stream>>>(acc);

    dim3 grid(BDIM, HDIM / TH);
    fused_kernel<<<grid, WDIM, 0, stream>>>(pred, mask, acc);

    finalize_kernel<<<1, 64, 0, stream>>>(acc, out);
}